// Round 3
// baseline (2328.051 us; speedup 1.0000x reference)
//
#include <hip/hip_runtime.h>

#define S_LEN 2048
#define NB 2
#define NH 32
#define NKV 8
#define HD 128
#define HID 4096
#define NQKV 6144

using bf16x8 = __attribute__((ext_vector_type(8))) __bf16;
using f32x4  = __attribute__((ext_vector_type(4))) float;

__device__ __forceinline__ ushort f2b(float f) {
  uint u = __builtin_bit_cast(uint, f);
  u += 0x7fffu + ((u >> 16) & 1u);
  return (ushort)(u >> 16);
}
__device__ __forceinline__ float b2f(ushort h) {
  uint u = ((uint)h) << 16;
  return __builtin_bit_cast(float, u);
}

__device__ __forceinline__ void gld16(const void* g, void* l) {
  __builtin_amdgcn_global_load_lds((const __attribute__((address_space(1))) void*)g,
                                   (__attribute__((address_space(3))) void*)l, 16, 0, 0);
}

__device__ __forceinline__ void stc(float* C, size_t i, float v)  { C[i] = v; }
__device__ __forceinline__ void stc(ushort* C, size_t i, float v) { C[i] = f2b(v); }

// ---------------- bf16 MFMA GEMM: C[M][N] = A[M][K](lda) * W[K][N] ----------------
// A: f32 (converted in staging) if AF32, else bf16 (gld16 fast path).
// W: f32, transposed+converted to bf16 during staging (Bs[n][k]).
template <bool AF32, typename OutT>
__global__ __launch_bounds__(256) void gemm_nt(const void* __restrict__ Av,
                                               const float* __restrict__ W,
                                               OutT* __restrict__ C,
                                               int M, int N, int K, int lda) {
  __shared__ ushort As[128 * 32];
  __shared__ ushort Bs[128 * 32];
  const int tid  = threadIdx.x;
  const int wave = tid >> 6;
  const int lane = tid & 63;
  const int lr = lane & 15, lg = lane >> 4;
  const int m0 = blockIdx.y * 128, n0 = blockIdx.x * 128;
  const int wm = (wave >> 1) * 64, wn = (wave & 1) * 64;

  f32x4 acc[4][4];
#pragma unroll
  for (int i = 0; i < 4; ++i)
#pragma unroll
    for (int j = 0; j < 4; ++j) acc[i][j] = (f32x4){0.f, 0.f, 0.f, 0.f};

  for (int kt = 0; kt < K; kt += 32) {
    __syncthreads();
    // ---- A staging ----
    if constexpr (AF32) {
      const float* A = (const float*)Av;
#pragma unroll
      for (int it = 0; it < 2; ++it) {
        const int idx = it * 256 + tid;
        const int row = idx >> 2, ch = idx & 3;
        const float* src = A + (size_t)(m0 + row) * lda + kt + ch * 8;
        float4 v0 = *(const float4*)src;
        float4 v1 = *(const float4*)(src + 4);
        ushort* d = As + row * 32 + ch * 8;
        *(ushort4*)d       = make_ushort4(f2b(v0.x), f2b(v0.y), f2b(v0.z), f2b(v0.w));
        *(ushort4*)(d + 4) = make_ushort4(f2b(v1.x), f2b(v1.y), f2b(v1.z), f2b(v1.w));
      }
    } else {
      const ushort* A = (const ushort*)Av;
#pragma unroll
      for (int it = 0; it < 2; ++it) {
        const int cbase = it * 256 + wave * 64;  // wave-uniform LDS base
        const int c = cbase + lane;
        const int row = c >> 2, kc = c & 3;
        gld16(A + (size_t)(m0 + row) * lda + kt + kc * 8, As + cbase * 8);
      }
    }
    // ---- B staging: W[kt..kt+31][n0..n0+127] f32 -> Bs[n][k] bf16 ----
#pragma unroll
    for (int it = 0; it < 2; ++it) {
      const int idx = it * 256 + tid;
      const int nc = idx & 15, kk = idx >> 4;
      const float* src = W + (size_t)(kt + kk) * N + n0 + nc * 8;
      float4 v0 = *(const float4*)src;
      float4 v1 = *(const float4*)(src + 4);
      float vals[8] = {v0.x, v0.y, v0.z, v0.w, v1.x, v1.y, v1.z, v1.w};
#pragma unroll
      for (int u = 0; u < 8; ++u) Bs[(nc * 8 + u) * 32 + kk] = f2b(vals[u]);
    }
    __syncthreads();
    bf16x8 af[4], bfg[4];
#pragma unroll
    for (int i = 0; i < 4; ++i) {
      af[i]  = *(const bf16x8*)(As + (wm + i * 16 + lr) * 32 + lg * 8);
      bfg[i] = *(const bf16x8*)(Bs + (wn + i * 16 + lr) * 32 + lg * 8);
    }
#pragma unroll
    for (int i = 0; i < 4; ++i)
#pragma unroll
      for (int j = 0; j < 4; ++j)
        acc[i][j] = __builtin_amdgcn_mfma_f32_16x16x32_bf16(af[i], bfg[j], acc[i][j], 0, 0, 0);
  }

#pragma unroll
  for (int i = 0; i < 4; ++i)
#pragma unroll
    for (int j = 0; j < 4; ++j)
#pragma unroll
      for (int r = 0; r < 4; ++r) {
        const int row = m0 + wm + i * 16 + lg * 4 + r;
        const int col = n0 + wn + j * 16 + lr;
        stc(C, (size_t)row * N + col, acc[i][j][r]);
      }
}

// ---------------- RoPE in-place on q/k heads of qkv (bf16) ----------------
// positions == arange(S) by construction.
__global__ __launch_bounds__(256) void rope_qk(ushort* __restrict__ qkv) {
  int t = blockIdx.x * 256 + threadIdx.x;
  const int i = t & 63;
  t >>= 6;
  const int head  = t % (NH + NKV);
  const int token = t / (NH + NKV);
  const int s = token & (S_LEN - 1);
  const size_t base = (size_t)token * NQKV + (head < NH ? head * HD : HID + (head - NH) * HD);
  const float x1 = b2f(qkv[base + i]);
  const float x2 = b2f(qkv[base + 64 + i]);
  // inv_freq = 10000^(-i/64) = 2^(-i * log2(10000)/64)
  const float invf = exp2f(-(float)i * 0.2076205059304602f);
  const float fr = (float)s * invf;
  float cs, sn;
  sincosf(fr, &sn, &cs);  // NOTE: sincosf writes SIN first, COS second
  float o1 = x1 * cs - x2 * sn;
  float o2 = x2 * cs + x1 * sn;
  if (head < NH) {
    o1 *= 0.08838834764831845f;  // 1/sqrt(128) pre-applied to Q
    o2 *= 0.08838834764831845f;
  }
  qkv[base + i]      = f2b(o1);
  qkv[base + 64 + i] = f2b(o2);
}

// ---------------- V: qkv[token][5120+kv*128+d] -> Vt[b*8+kv][d][s] ----------------
__global__ void vtrans(const ushort* __restrict__ qkv, ushort* __restrict__ Vt) {
  __shared__ ushort tile[32][33];
  const int dt = blockIdx.x * 32, st = blockIdx.y * 32, bk = blockIdx.z;
  const int b = bk >> 3, kv = bk & 7;
  const int x = threadIdx.x, y = threadIdx.y;  // (32,8)
#pragma unroll
  for (int i = 0; i < 32; i += 8)
    tile[y + i][x] =
        qkv[(size_t)(b * S_LEN + st + y + i) * NQKV + 5120 + kv * HD + dt + x];
  __syncthreads();
#pragma unroll
  for (int i = 0; i < 32; i += 8)
    Vt[((size_t)bk * HD + dt + y + i) * S_LEN + st + x] = tile[x][y + i];
}

// ---------------- flash attention: 1 wave per (b, h, 16 q rows) ----------------
// Reads Q,K in-place from qkv (stride NQKV); writes O back into the q slots.
__global__ __launch_bounds__(64) void attn_fa(ushort* __restrict__ qkv,
                                              const ushort* __restrict__ Vt) {
  const int qt = blockIdx.x, h = blockIdx.y, b = blockIdx.z;
  const int lane = threadIdx.x, lr = lane & 15, lg = lane >> 4;
  const int q0 = qt * 16;
  const int kvh = h >> 2;  // 4 q heads per kv head
  const ushort* Q = qkv + (size_t)(b * S_LEN + q0) * NQKV + h * HD;
  const ushort* K = qkv + (size_t)(b * S_LEN) * NQKV + HID + kvh * HD;
  const ushort* V = Vt + (size_t)(b * NKV + kvh) * HD * S_LEN;

  bf16x8 qf[4];
#pragma unroll
  for (int kb = 0; kb < 4; ++kb)
    qf[kb] = *(const bf16x8*)(Q + (size_t)lr * NQKV + kb * 32 + lg * 8);

  f32x4 o[8];
#pragma unroll
  for (int c = 0; c < 8; ++c) o[c] = (f32x4){0.f, 0.f, 0.f, 0.f};
  float mi[4], li[4];
#pragma unroll
  for (int r = 0; r < 4; ++r) { mi[r] = -1e30f; li[r] = 0.f; }

  __shared__ ushort P[16 * 32];
  const int kend = q0 + 16;
  for (int k0 = 0; k0 < kend; k0 += 32) {
    const int kr0 = k0 + lr;
    const int kr1 = k0 + 16 + lr;
    f32x4 s0 = (f32x4){0.f, 0.f, 0.f, 0.f};
    f32x4 s1 = (f32x4){0.f, 0.f, 0.f, 0.f};
#pragma unroll
    for (int kb = 0; kb < 4; ++kb) {
      bf16x8 k0f = *(const bf16x8*)(K + (size_t)kr0 * NQKV + kb * 32 + lg * 8);
      bf16x8 k1f = *(const bf16x8*)(K + (size_t)kr1 * NQKV + kb * 32 + lg * 8);
      s0 = __builtin_amdgcn_mfma_f32_16x16x32_bf16(qf[kb], k0f, s0, 0, 0, 0);
      s1 = __builtin_amdgcn_mfma_f32_16x16x32_bf16(qf[kb], k1f, s1, 0, 0, 0);
    }
#pragma unroll
    for (int r = 0; r < 4; ++r) {
      const int q = q0 + lg * 4 + r;
      float v0 = (k0 + lr      <= q) ? s0[r] : -1e30f;
      float v1 = (k0 + 16 + lr <= q) ? s1[r] : -1e30f;
      float mx = fmaxf(v0, v1);
#pragma unroll
      for (int off = 1; off < 16; off <<= 1) mx = fmaxf(mx, __shfl_xor(mx, off));
      const float mn = fmaxf(mi[r], mx);
      const float al = __expf(mi[r] - mn);
      const float p0 = __expf(v0 - mn);
      const float p1 = __expf(v1 - mn);
      float rs = p0 + p1;
#pragma unroll
      for (int off = 1; off < 16; off <<= 1) rs += __shfl_xor(rs, off);
      li[r] = li[r] * al + rs;
      mi[r] = mn;
#pragma unroll
      for (int c = 0; c < 8; ++c) o[c][r] *= al;
      P[(lg * 4 + r) * 32 + lr]      = f2b(p0);
      P[(lg * 4 + r) * 32 + 16 + lr] = f2b(p1);
    }
    __syncthreads();
    const bf16x8 pa = *(const bf16x8*)(P + lr * 32 + lg * 8);
    const int ko = k0 + lg * 8;
#pragma unroll
    for (int c = 0; c < 8; ++c) {
      bf16x8 vf = *(const bf16x8*)(V + (size_t)(c * 16 + lr) * S_LEN + ko);
      o[c] = __builtin_amdgcn_mfma_f32_16x16x32_bf16(pa, vf, o[c], 0, 0, 0);
    }
    __syncthreads();
  }
#pragma unroll
  for (int r = 0; r < 4; ++r) {
    const float inv = 1.f / li[r];
    const size_t row = (size_t)(b * S_LEN + q0 + lg * 4 + r) * NQKV + h * HD;
#pragma unroll
    for (int c = 0; c < 8; ++c) qkv[row + c * 16 + lr] = f2b(o[c][r] * inv);
  }
}

extern "C" void kernel_launch(void* const* d_in, const int* in_sizes, int n_in,
                              void* d_out, int out_size, void* d_ws, size_t ws_size,
                              hipStream_t stream) {
  const float* hidden = (const float*)d_in[1];
  const float* w_qkv  = (const float*)d_in[2];
  const float* w_o    = (const float*)d_in[3];
  float* out = (float*)d_out;
  char* ws = (char*)d_ws;

  // workspace layout (56 MiB total):
  // [0, 50331648)        : qkv bf16 [4096][6144]; rope in-place; attn output
  //                        written back into the q slots (cols [0,4096))
  // [50331648, 58720256) : Vt bf16 [16][128][2048] (8 MiB)
  ushort* qkvb = (ushort*)(ws);
  ushort* Vt   = (ushort*)(ws + 50331648);

  // 1) qkv = hidden @ w_qkv  (A: f32 fused-convert, B: f32 fused-transpose)
  gemm_nt<true, ushort><<<dim3(48, 32), 256, 0, stream>>>(
      hidden, w_qkv, qkvb, NB * S_LEN, NQKV, HID, HID);
  // 2) RoPE in-place on q (+scale 1/sqrt(D)) and k heads
  rope_qk<<<40960, 256, 0, stream>>>(qkvb);
  // 3) V -> Vt[d][s]
  vtrans<<<dim3(4, 64, 16), dim3(32, 8), 0, stream>>>(qkvb, Vt);
  // 4) flash attention, output in-place into q slots
  attn_fa<<<dim3(128, 32, 2), 64, 0, stream>>>(qkvb, Vt);
  // 5) out = attn @ w_o  (A: bf16 gld16 path with lda=6144, B: f32 fused-transpose)
  gemm_nt<false, float><<<dim3(32, 32), 256, 0, stream>>>(
      qkvb, w_o, out, NB * S_LEN, HID, HID, NQKV);
}

// Round 4
// 1345.205 us; speedup vs baseline: 1.7306x; 1.7306x over previous
//
#include <hip/hip_runtime.h>

#define S_LEN 2048
#define NB 2
#define NH 32
#define NKV 8
#define HD 128
#define HID 4096
#define NQKV 6144

using bf16x8 = __attribute__((ext_vector_type(8))) __bf16;
using f32x4  = __attribute__((ext_vector_type(4))) float;

__device__ __forceinline__ ushort f2b(float f) {
  uint u = __builtin_bit_cast(uint, f);
  u += 0x7fffu + ((u >> 16) & 1u);
  return (ushort)(u >> 16);
}
__device__ __forceinline__ float b2f(ushort h) {
  uint u = ((uint)h) << 16;
  return __builtin_bit_cast(float, u);
}

__device__ __forceinline__ void gld16(const void* g, void* l) {
  __builtin_amdgcn_global_load_lds((const __attribute__((address_space(1))) void*)g,
                                   (__attribute__((address_space(3))) void*)l, 16, 0, 0);
}

__device__ __forceinline__ void stc(float* C, size_t i, float v)  { C[i] = v; }
__device__ __forceinline__ void stc(ushort* C, size_t i, float v) { C[i] = f2b(v); }

// ---------------- f32 -> bf16 elementwise ----------------
__global__ void cvt_bf16(const float* __restrict__ src, ushort* __restrict__ dst, int n) {
  int i = (blockIdx.x * 256 + threadIdx.x) * 4;
  if (i < n) {
    float4 v = *(const float4*)(src + i);
    *(ushort4*)(dst + i) = make_ushort4(f2b(v.x), f2b(v.y), f2b(v.z), f2b(v.w));
  }
}

// ---------------- f32 [R][C] -> bf16 [C][R] transpose (padded tile, conflict-free) ----
__global__ void trans_f32_bf16(const float* __restrict__ src, ushort* __restrict__ dst,
                               int R, int C) {
  __shared__ float tile[32][33];
  const int c0 = blockIdx.x * 32, r0 = blockIdx.y * 32;
  const int x = threadIdx.x, y = threadIdx.y;  // block (32,8)
#pragma unroll
  for (int i = 0; i < 32; i += 8)
    tile[y + i][x] = src[(size_t)(r0 + y + i) * C + (c0 + x)];
  __syncthreads();
#pragma unroll
  for (int i = 0; i < 32; i += 8)
    dst[(size_t)(c0 + y + i) * R + (r0 + x)] = f2b(tile[x][y + i]);
}

// ---------------- bf16 NT GEMM (m97 structure): C[M][N] = A[M][K] * Bt[N][K]^T ------
// Both operands staged global->LDS via global_load_lds width=16. No VALU in staging.
template <typename OutT>
__global__ __launch_bounds__(256) void gemm_nt(const ushort* __restrict__ A,
                                               const ushort* __restrict__ Bt,
                                               OutT* __restrict__ C,
                                               int M, int N, int K, int lda, int ldb) {
  __shared__ ushort As[128 * 32];
  __shared__ ushort Bs[128 * 32];
  const int tid  = threadIdx.x;
  const int wave = tid >> 6;
  const int lane = tid & 63;
  const int lr = lane & 15, lg = lane >> 4;
  const int m0 = blockIdx.y * 128, n0 = blockIdx.x * 128;
  const int wm = (wave >> 1) * 64, wn = (wave & 1) * 64;

  f32x4 acc[4][4];
#pragma unroll
  for (int i = 0; i < 4; ++i)
#pragma unroll
    for (int j = 0; j < 4; ++j) acc[i][j] = (f32x4){0.f, 0.f, 0.f, 0.f};

  for (int kt = 0; kt < K; kt += 32) {
    __syncthreads();
#pragma unroll
    for (int it = 0; it < 2; ++it) {
      const int cbase = it * 256 + wave * 64;  // wave-uniform LDS base
      const int c = cbase + lane;
      const int row = c >> 2, kc = c & 3;
      gld16(A  + (size_t)(m0 + row) * lda + kt + kc * 8, As + cbase * 8);
      gld16(Bt + (size_t)(n0 + row) * ldb + kt + kc * 8, Bs + cbase * 8);
    }
    __syncthreads();
    bf16x8 af[4], bfg[4];
#pragma unroll
    for (int i = 0; i < 4; ++i) {
      af[i]  = *(const bf16x8*)(As + (wm + i * 16 + lr) * 32 + lg * 8);
      bfg[i] = *(const bf16x8*)(Bs + (wn + i * 16 + lr) * 32 + lg * 8);
    }
#pragma unroll
    for (int i = 0; i < 4; ++i)
#pragma unroll
      for (int j = 0; j < 4; ++j)
        acc[i][j] = __builtin_amdgcn_mfma_f32_16x16x32_bf16(af[i], bfg[j], acc[i][j], 0, 0, 0);
  }

#pragma unroll
  for (int i = 0; i < 4; ++i)
#pragma unroll
    for (int j = 0; j < 4; ++j)
#pragma unroll
      for (int r = 0; r < 4; ++r) {
        const int row = m0 + wm + i * 16 + lg * 4 + r;
        const int col = n0 + wn + j * 16 + lr;
        stc(C, (size_t)row * N + col, acc[i][j][r]);
      }
}

// ---------------- RoPE in-place on q/k heads of qkv (bf16) ----------------
__global__ __launch_bounds__(256) void rope_qk(ushort* __restrict__ qkv) {
  int t = blockIdx.x * 256 + threadIdx.x;
  const int i = t & 63;
  t >>= 6;
  const int head  = t % (NH + NKV);
  const int token = t / (NH + NKV);
  const int s = token & (S_LEN - 1);
  const size_t base = (size_t)token * NQKV + (head < NH ? head * HD : HID + (head - NH) * HD);
  const float x1 = b2f(qkv[base + i]);
  const float x2 = b2f(qkv[base + 64 + i]);
  const float invf = exp2f(-(float)i * 0.2076205059304602f);  // 10000^(-i/64)
  const float fr = (float)s * invf;
  float cs, sn;
  sincosf(fr, &sn, &cs);  // sincosf writes SIN first, COS second
  float o1 = x1 * cs - x2 * sn;
  float o2 = x2 * cs + x1 * sn;
  if (head < NH) {
    o1 *= 0.08838834764831845f;  // 1/sqrt(128) pre-applied to Q
    o2 *= 0.08838834764831845f;
  }
  qkv[base + i]      = f2b(o1);
  qkv[base + 64 + i] = f2b(o2);
}

// ---------------- V: qkv[token][5120+kv*128+d] -> Vt[b*8+kv][d][s] ----------------
__global__ void vtrans(const ushort* __restrict__ qkv, ushort* __restrict__ Vt) {
  __shared__ ushort tile[32][33];
  const int dt = blockIdx.x * 32, st = blockIdx.y * 32, bk = blockIdx.z;
  const int b = bk >> 3, kv = bk & 7;
  const int x = threadIdx.x, y = threadIdx.y;  // (32,8)
#pragma unroll
  for (int i = 0; i < 32; i += 8)
    tile[y + i][x] =
        qkv[(size_t)(b * S_LEN + st + y + i) * NQKV + 5120 + kv * HD + dt + x];
  __syncthreads();
#pragma unroll
  for (int i = 0; i < 32; i += 8)
    Vt[((size_t)bk * HD + dt + y + i) * S_LEN + st + x] = tile[x][y + i];
}

// ---------------- flash attention: 1 wave per (b, h, 16 q rows) ----------------
__global__ __launch_bounds__(64) void attn_fa(ushort* __restrict__ qkv,
                                              const ushort* __restrict__ Vt) {
  const int qt = blockIdx.x, h = blockIdx.y, b = blockIdx.z;
  const int lane = threadIdx.x, lr = lane & 15, lg = lane >> 4;
  const int q0 = qt * 16;
  const int kvh = h >> 2;  // 4 q heads per kv head
  const ushort* Q = qkv + (size_t)(b * S_LEN + q0) * NQKV + h * HD;
  const ushort* K = qkv + (size_t)(b * S_LEN) * NQKV + HID + kvh * HD;
  const ushort* V = Vt + (size_t)(b * NKV + kvh) * HD * S_LEN;

  bf16x8 qf[4];
#pragma unroll
  for (int kb = 0; kb < 4; ++kb)
    qf[kb] = *(const bf16x8*)(Q + (size_t)lr * NQKV + kb * 32 + lg * 8);

  f32x4 o[8];
#pragma unroll
  for (int c = 0; c < 8; ++c) o[c] = (f32x4){0.f, 0.f, 0.f, 0.f};
  float mi[4], li[4];
#pragma unroll
  for (int r = 0; r < 4; ++r) { mi[r] = -1e30f; li[r] = 0.f; }

  __shared__ ushort P[16 * 32];
  const int kend = q0 + 16;
  for (int k0 = 0; k0 < kend; k0 += 32) {
    const int kr0 = k0 + lr;
    const int kr1 = k0 + 16 + lr;
    f32x4 s0 = (f32x4){0.f, 0.f, 0.f, 0.f};
    f32x4 s1 = (f32x4){0.f, 0.f, 0.f, 0.f};
#pragma unroll
    for (int kb = 0; kb < 4; ++kb) {
      bf16x8 k0f = *(const bf16x8*)(K + (size_t)kr0 * NQKV + kb * 32 + lg * 8);
      bf16x8 k1f = *(const bf16x8*)(K + (size_t)kr1 * NQKV + kb * 32 + lg * 8);
      s0 = __builtin_amdgcn_mfma_f32_16x16x32_bf16(qf[kb], k0f, s0, 0, 0, 0);
      s1 = __builtin_amdgcn_mfma_f32_16x16x32_bf16(qf[kb], k1f, s1, 0, 0, 0);
    }
#pragma unroll
    for (int r = 0; r < 4; ++r) {
      const int q = q0 + lg * 4 + r;
      float v0 = (k0 + lr      <= q) ? s0[r] : -1e30f;
      float v1 = (k0 + 16 + lr <= q) ? s1[r] : -1e30f;
      float mx = fmaxf(v0, v1);
#pragma unroll
      for (int off = 1; off < 16; off <<= 1) mx = fmaxf(mx, __shfl_xor(mx, off));
      const float mn = fmaxf(mi[r], mx);
      const float al = __expf(mi[r] - mn);
      const float p0 = __expf(v0 - mn);
      const float p1 = __expf(v1 - mn);
      float rs = p0 + p1;
#pragma unroll
      for (int off = 1; off < 16; off <<= 1) rs += __shfl_xor(rs, off);
      li[r] = li[r] * al + rs;
      mi[r] = mn;
#pragma unroll
      for (int c = 0; c < 8; ++c) o[c][r] *= al;
      P[(lg * 4 + r) * 32 + lr]      = f2b(p0);
      P[(lg * 4 + r) * 32 + 16 + lr] = f2b(p1);
    }
    __syncthreads();
    const bf16x8 pa = *(const bf16x8*)(P + lr * 32 + lg * 8);
    const int ko = k0 + lg * 8;
#pragma unroll
    for (int c = 0; c < 8; ++c) {
      bf16x8 vf = *(const bf16x8*)(V + (size_t)(c * 16 + lr) * S_LEN + ko);
      o[c] = __builtin_amdgcn_mfma_f32_16x16x32_bf16(pa, vf, o[c], 0, 0, 0);
    }
    __syncthreads();
  }
#pragma unroll
  for (int r = 0; r < 4; ++r) {
    const float inv = 1.f / li[r];
    const size_t row = (size_t)(b * S_LEN + q0 + lg * 4 + r) * NQKV + h * HD;
#pragma unroll
    for (int c = 0; c < 8; ++c) qkv[row + c * 16 + lr] = f2b(o[c][r] * inv);
  }
}

extern "C" void kernel_launch(void* const* d_in, const int* in_sizes, int n_in,
                              void* d_out, int out_size, void* d_ws, size_t ws_size,
                              hipStream_t stream) {
  const float* hidden = (const float*)d_in[1];
  const float* w_qkv  = (const float*)d_in[2];
  const float* w_o    = (const float*)d_in[3];
  float* out = (float*)d_out;
  char* ws = (char*)d_ws;

  // workspace layout (128 MiB; bit-identical results across R1/R2 layouts imply
  // ws_size >= 128 MiB):
  // R0 [0, 48 MiB)   : wqkvT bf16 [6144][4096]; after gemm1: Vt bf16 [16][128][2048]
  // R1 [48, 80 MiB)  : hb bf16 [4096][4096];    after gemm1: woT bf16 [4096][4096]
  // R2 [80, 128 MiB) : qkv bf16 [4096][6144]; rope in-place; attn into q slots
  ushort* wqkvT = (ushort*)(ws);
  ushort* Vt    = (ushort*)(ws);
  ushort* hb    = (ushort*)(ws + (48u << 20));
  ushort* woT   = (ushort*)(ws + (48u << 20));
  ushort* qkvb  = (ushort*)(ws + (80u << 20));

  // 1) weight + activation prep
  trans_f32_bf16<<<dim3(192, 128), dim3(32, 8), 0, stream>>>(w_qkv, wqkvT, HID, NQKV);
  cvt_bf16<<<16384, 256, 0, stream>>>(hidden, hb, NB * S_LEN * HID);
  // 2) qkv = hb @ wqkvT^T
  gemm_nt<ushort><<<dim3(48, 32), 256, 0, stream>>>(
      hb, wqkvT, qkvb, NB * S_LEN, NQKV, HID, HID, HID);
  // 3) RoPE in-place (q pre-scaled by 1/sqrt(D))
  rope_qk<<<40960, 256, 0, stream>>>(qkvb);
  // 4) V -> Vt[d][s]  (into dead wqkvT region)
  vtrans<<<dim3(4, 64, 16), dim3(32, 8), 0, stream>>>(qkvb, Vt);
  // 5) w_o -> woT (into dead hb region)
  trans_f32_bf16<<<dim3(128, 128), dim3(32, 8), 0, stream>>>(w_o, woT, HID, HID);
  // 6) flash attention, output in-place into q slots
  attn_fa<<<dim3(128, 32, 2), 64, 0, stream>>>(qkvb, Vt);
  // 7) out = attn @ woT^T
  gemm_nt<float><<<dim3(32, 32), 256, 0, stream>>>(
      qkvb, woT, out, NB * S_LEN, HID, HID, NQKV, HID);
}